// Round 1
// baseline (1230.026 us; speedup 1.0000x reference)
//
#include <hip/hip_runtime.h>
#include <hip/hip_bf16.h>

#define DM   1024
#define NE   8
#define DFF  4096
#define NTOK 4096

typedef __attribute__((ext_vector_type(8))) short bf16x8;
typedef __attribute__((ext_vector_type(4))) float f32x4;
typedef __attribute__((ext_vector_type(4))) int   i32x4;

__device__ __forceinline__ short to_bf16(float f) {
  unsigned u = __float_as_uint(f);
  unsigned r = (u + 0x7fffu + ((u >> 16) & 1u)) >> 16;   // RNE
  return (short)r;
}

// ---------------- router ----------------
__global__ __launch_bounds__(256) void router_kernel(
    const float* __restrict__ x, const float* __restrict__ gw,
    int* __restrict__ cnt, float* __restrict__ psum,
    int* __restrict__ pairs, float* __restrict__ pairW)
{
  __shared__ float gws[DM * NE];
  const int tid = threadIdx.x;
  for (int i = tid * 4; i < DM * NE; i += 256 * 4)
    *reinterpret_cast<float4*>(&gws[i]) = *reinterpret_cast<const float4*>(&gw[i]);
  __syncthreads();

  const int n = blockIdx.x * 256 + tid;
  float acc[NE];
#pragma unroll
  for (int e = 0; e < NE; ++e) acc[e] = 0.f;

  const float4* xr = reinterpret_cast<const float4*>(x + (size_t)n * DM);
  for (int d4 = 0; d4 < DM / 4; ++d4) {
    float4 v = xr[d4];
    const float* gp = &gws[d4 * 4 * NE];
    float xv;
#pragma unroll
    for (int dd = 0; dd < 4; ++dd) {
      xv = (dd == 0) ? v.x : (dd == 1) ? v.y : (dd == 2) ? v.z : v.w;
#pragma unroll
      for (int e = 0; e < NE; ++e) acc[e] = fmaf(xv, gp[dd * NE + e], acc[e]);
    }
  }

  // full softmax for aux loss
  float mx = acc[0];
#pragma unroll
  for (int e = 1; e < NE; ++e) mx = fmaxf(mx, acc[e]);
  float p[NE], s = 0.f;
#pragma unroll
  for (int e = 0; e < NE; ++e) { p[e] = expf(acc[e] - mx); s += p[e]; }
  float inv = 1.f / s;
#pragma unroll
  for (int e = 0; e < NE; ++e) {
    float v = p[e] * inv;
#pragma unroll
    for (int o = 32; o > 0; o >>= 1) v += __shfl_xor(v, o);
    if ((tid & 63) == 0) atomicAdd(&psum[e], v);
  }

  // top-2 (ties -> lower index, matches lax.top_k)
  float v0 = -1e30f, v1 = -1e30f; int i0 = 0, i1 = 0;
#pragma unroll
  for (int e = 0; e < NE; ++e) {
    float l = acc[e];
    if (l > v0) { v1 = v0; i1 = i0; v0 = l; i0 = e; }
    else if (l > v1) { v1 = l; i1 = e; }
  }
  float e1 = expf(v1 - v0);
  float den = 1.f + e1;
  pairW[n * 2]     = 1.f / den;
  pairW[n * 2 + 1] = e1 / den;
  int p0 = atomicAdd(&cnt[i0], 1); pairs[i0 * NTOK + p0] = n * 2;
  int p1 = atomicAdd(&cnt[i1], 1); pairs[i1 * NTOK + p1] = n * 2 + 1;
}

// ---------------- scan + aux ----------------
__global__ void finalize_kernel(const int* __restrict__ cnt, int* __restrict__ off,
                                const float* __restrict__ psum, float* __restrict__ aux)
{
  if (threadIdx.x == 0 && blockIdx.x == 0) {
    int o = 0;
    for (int e = 0; e < NE; ++e) { off[e] = o; o += cnt[e]; }
    off[NE] = o;
    float a = 0.f;
    for (int e = 0; e < NE; ++e) { float me = psum[e] * (1.f / NTOK); a += me * me; }
    aux[0] = a * (float)NE;
  }
}

// ---------------- GEMM1: h = gelu(x_gathered @ w1[e]) ----------------
__global__ __launch_bounds__(256) void gemm1_kernel(
    const float* __restrict__ x, const float* __restrict__ w1,
    const int* __restrict__ cnt, const int* __restrict__ off,
    const int* __restrict__ pairs, short* __restrict__ h)
{
  const int e  = blockIdx.z;
  const int M  = cnt[e];
  const int m0 = blockIdx.x * 128;
  if (m0 >= M) return;
  const int ff0  = blockIdx.y * 128;
  const int base = off[e];

  __shared__ __attribute__((aligned(16))) short Al[128][40];
  __shared__ __attribute__((aligned(16))) short Bl[128][40];

  const int tid  = threadIdx.x;
  const int lane = tid & 63;
  const int wave = tid >> 6;
  const int wm = wave >> 1, wn = wave & 1;

  // A staging: thread -> (row, 16-col half)
  const int arow = tid >> 1;
  const int acol = (tid & 1) * 16;
  int gi = m0 + arow; if (gi > M - 1) gi = M - 1;
  const int tok = pairs[e * NTOK + gi] >> 1;
  const float* xrow = x + (size_t)tok * DM;

  // B staging: thread -> (ff col, 16-k group), loads strided along k (lane-coalesced over ff)
  const int bcol = tid & 127;
  const int bk   = (tid >> 7) * 16;
  const float* wcol = w1 + (size_t)e * DM * DFF + (size_t)bk * DFF + ff0 + bcol;

  f32x4 acc[4][4];
#pragma unroll
  for (int i = 0; i < 4; ++i)
#pragma unroll
    for (int j = 0; j < 4; ++j) acc[i][j] = (f32x4){0.f, 0.f, 0.f, 0.f};

  const int lrow = lane & 15;
  const int lk   = (lane >> 4) * 8;

  for (int k0 = 0; k0 < DM; k0 += 32) {
    float4 a0 = *reinterpret_cast<const float4*>(xrow + k0 + acol);
    float4 a1 = *reinterpret_cast<const float4*>(xrow + k0 + acol + 4);
    float4 a2 = *reinterpret_cast<const float4*>(xrow + k0 + acol + 8);
    float4 a3 = *reinterpret_cast<const float4*>(xrow + k0 + acol + 12);
    union { short s[8]; bf16x8 v; } pa0, pa1;
    pa0.s[0]=to_bf16(a0.x); pa0.s[1]=to_bf16(a0.y); pa0.s[2]=to_bf16(a0.z); pa0.s[3]=to_bf16(a0.w);
    pa0.s[4]=to_bf16(a1.x); pa0.s[5]=to_bf16(a1.y); pa0.s[6]=to_bf16(a1.z); pa0.s[7]=to_bf16(a1.w);
    pa1.s[0]=to_bf16(a2.x); pa1.s[1]=to_bf16(a2.y); pa1.s[2]=to_bf16(a2.z); pa1.s[3]=to_bf16(a2.w);
    pa1.s[4]=to_bf16(a3.x); pa1.s[5]=to_bf16(a3.y); pa1.s[6]=to_bf16(a3.z); pa1.s[7]=to_bf16(a3.w);
    *reinterpret_cast<bf16x8*>(&Al[arow][acol])     = pa0.v;
    *reinterpret_cast<bf16x8*>(&Al[arow][acol + 8]) = pa1.v;

    const float* wp = wcol + (size_t)k0 * DFF;
    union { short s[8]; bf16x8 v; } pb0, pb1;
#pragma unroll
    for (int j = 0; j < 8; ++j)  pb0.s[j] = to_bf16(wp[(size_t)j * DFF]);
#pragma unroll
    for (int j = 0; j < 8; ++j)  pb1.s[j] = to_bf16(wp[(size_t)(j + 8) * DFF]);
    *reinterpret_cast<bf16x8*>(&Bl[bcol][bk])     = pb0.v;
    *reinterpret_cast<bf16x8*>(&Bl[bcol][bk + 8]) = pb1.v;

    __syncthreads();

    bf16x8 af[4], bfv[4];
#pragma unroll
    for (int i = 0; i < 4; ++i)
      af[i] = *reinterpret_cast<const bf16x8*>(&Al[wm * 64 + i * 16 + lrow][lk]);
#pragma unroll
    for (int j = 0; j < 4; ++j)
      bfv[j] = *reinterpret_cast<const bf16x8*>(&Bl[wn * 64 + j * 16 + lrow][lk]);
#pragma unroll
    for (int i = 0; i < 4; ++i)
#pragma unroll
      for (int j = 0; j < 4; ++j)
        acc[i][j] = __builtin_amdgcn_mfma_f32_16x16x32_bf16(af[i], bfv[j], acc[i][j], 0, 0, 0);

    __syncthreads();
  }

  const int rbase = wm * 64 + (lane >> 4) * 4;
  const int cbase = ff0 + wn * 64 + (lane & 15);
#pragma unroll
  for (int i = 0; i < 4; ++i) {
#pragma unroll
    for (int r = 0; r < 4; ++r) {
      const int grow = m0 + rbase + i * 16 + r;
      if (grow < M) {
#pragma unroll
        for (int j = 0; j < 4; ++j) {
          float v = acc[i][j][r];
          float g = 0.5f * v * (1.f + erff(v * 0.70710678118f));
          h[(size_t)(base + grow) * DFF + cbase + j * 16] = to_bf16(g);
        }
      }
    }
  }
}

// ---------------- GEMM2: out += weight * (h @ w2[e]) ----------------
__global__ __launch_bounds__(256) void gemm2_kernel(
    const short* __restrict__ h, const float* __restrict__ w2,
    const int* __restrict__ cnt, const int* __restrict__ off,
    const int* __restrict__ pairs, const float* __restrict__ pairW,
    float* __restrict__ out)
{
  const int e  = blockIdx.z;
  const int M  = cnt[e];
  const int m0 = blockIdx.x * 128;
  if (m0 >= M) return;
  const int d0   = blockIdx.y * 128;
  const int base = off[e];

  __shared__ __attribute__((aligned(16))) short Al[128][40];
  __shared__ __attribute__((aligned(16))) short Bl[128][40];

  const int tid  = threadIdx.x;
  const int lane = tid & 63;
  const int wave = tid >> 6;
  const int wm = wave >> 1, wn = wave & 1;

  const int arow = tid >> 1;
  const int acol = (tid & 1) * 16;
  int gi = m0 + arow; if (gi > M - 1) gi = M - 1;
  const short* hrow = h + (size_t)(base + gi) * DFF;

  const int bcol = tid & 127;
  const int bk   = (tid >> 7) * 16;
  const float* wcol = w2 + (size_t)e * DFF * DM + (size_t)bk * DM + d0 + bcol;

  f32x4 acc[4][4];
#pragma unroll
  for (int i = 0; i < 4; ++i)
#pragma unroll
    for (int j = 0; j < 4; ++j) acc[i][j] = (f32x4){0.f, 0.f, 0.f, 0.f};

  const int lrow = lane & 15;
  const int lk   = (lane >> 4) * 8;

  for (int k0 = 0; k0 < DFF; k0 += 32) {
    i32x4 av0 = *reinterpret_cast<const i32x4*>(hrow + k0 + acol);
    i32x4 av1 = *reinterpret_cast<const i32x4*>(hrow + k0 + acol + 8);
    *reinterpret_cast<i32x4*>(&Al[arow][acol])     = av0;
    *reinterpret_cast<i32x4*>(&Al[arow][acol + 8]) = av1;

    const float* wp = wcol + (size_t)k0 * DM;
    union { short s[8]; bf16x8 v; } pb0, pb1;
#pragma unroll
    for (int j = 0; j < 8; ++j)  pb0.s[j] = to_bf16(wp[(size_t)j * DM]);
#pragma unroll
    for (int j = 0; j < 8; ++j)  pb1.s[j] = to_bf16(wp[(size_t)(j + 8) * DM]);
    *reinterpret_cast<bf16x8*>(&Bl[bcol][bk])     = pb0.v;
    *reinterpret_cast<bf16x8*>(&Bl[bcol][bk + 8]) = pb1.v;

    __syncthreads();

    bf16x8 af[4], bfv[4];
#pragma unroll
    for (int i = 0; i < 4; ++i)
      af[i] = *reinterpret_cast<const bf16x8*>(&Al[wm * 64 + i * 16 + lrow][lk]);
#pragma unroll
    for (int j = 0; j < 4; ++j)
      bfv[j] = *reinterpret_cast<const bf16x8*>(&Bl[wn * 64 + j * 16 + lrow][lk]);
#pragma unroll
    for (int i = 0; i < 4; ++i)
#pragma unroll
      for (int j = 0; j < 4; ++j)
        acc[i][j] = __builtin_amdgcn_mfma_f32_16x16x32_bf16(af[i], bfv[j], acc[i][j], 0, 0, 0);

    __syncthreads();
  }

  const int rbase = wm * 64 + (lane >> 4) * 4;
  const int cbase = d0 + wn * 64 + (lane & 15);
#pragma unroll
  for (int i = 0; i < 4; ++i) {
#pragma unroll
    for (int r = 0; r < 4; ++r) {
      const int grow = m0 + rbase + i * 16 + r;
      if (grow < M) {
        const int pr  = pairs[e * NTOK + grow];
        const float w = pairW[pr];
        const int tk  = pr >> 1;
#pragma unroll
        for (int j = 0; j < 4; ++j)
          atomicAdd(&out[(size_t)tk * DM + cbase + j * 16], w * acc[i][j][r]);
      }
    }
  }
}

extern "C" void kernel_launch(void* const* d_in, const int* in_sizes, int n_in,
                              void* d_out, int out_size, void* d_ws, size_t ws_size,
                              hipStream_t stream)
{
  const float* x  = (const float*)d_in[0];
  const float* gw = (const float*)d_in[1];
  const float* w1 = (const float*)d_in[2];
  const float* w2 = (const float*)d_in[3];
  float* outf = (float*)d_out;

  int*   cnt   = (int*)d_ws;                                  // 8
  int*   off   = cnt + 8;                                     // 9
  float* psum  = (float*)(cnt + 20);                          // 8
  int*   pairs = (int*)((char*)d_ws + 512);                   // 8*4096 ints
  float* pairW = (float*)((char*)d_ws + 512 + NE * NTOK * 4); // 8192 floats
  short* h     = (short*)((char*)d_ws + (1 << 20));           // 8192 x 4096 bf16

  hipMemsetAsync(d_ws, 0, 512, stream);
  hipMemsetAsync(d_out, 0, (size_t)out_size * sizeof(float), stream);

  router_kernel<<<NTOK / 256, 256, 0, stream>>>(x, gw, cnt, psum, pairs, pairW);
  finalize_kernel<<<1, 64, 0, stream>>>(cnt, off, psum, outf + (size_t)NTOK * DM);
  gemm1_kernel<<<dim3(32, DFF / 128, NE), 256, 0, stream>>>(x, w1, cnt, off, pairs, h);
  gemm2_kernel<<<dim3(32, DM / 128, NE), 256, 0, stream>>>(h, w2, cnt, off, pairs, pairW, outf);
}

// Round 2
// 461.586 us; speedup vs baseline: 2.6648x; 2.6648x over previous
//
#include <hip/hip_runtime.h>
#include <hip/hip_bf16.h>

#define DM   1024
#define NE   8
#define DFF  4096
#define NTOK 4096

typedef __attribute__((ext_vector_type(8))) short bf16x8;
typedef __attribute__((ext_vector_type(4))) float f32x4;

__device__ __forceinline__ short to_bf16(float f) {
  unsigned u = __float_as_uint(f);
  unsigned r = (u + 0x7fffu + ((u >> 16) & 1u)) >> 16;   // RNE
  return (short)r;
}

__device__ __forceinline__ void gl16(const void* g, void* l) {
  __builtin_amdgcn_global_load_lds(
      (const __attribute__((address_space(1))) unsigned*)g,
      (__attribute__((address_space(3))) unsigned*)l, 16, 0, 0);
}

// ---------------- router (unchanged, proven) ----------------
__global__ __launch_bounds__(256) void router_kernel(
    const float* __restrict__ x, const float* __restrict__ gw,
    int* __restrict__ cnt, float* __restrict__ psum,
    int* __restrict__ pairs, float* __restrict__ pairW)
{
  __shared__ float gws[DM * NE];
  const int tid = threadIdx.x;
  for (int i = tid * 4; i < DM * NE; i += 256 * 4)
    *reinterpret_cast<float4*>(&gws[i]) = *reinterpret_cast<const float4*>(&gw[i]);
  __syncthreads();

  const int n = blockIdx.x * 256 + tid;
  float acc[NE];
#pragma unroll
  for (int e = 0; e < NE; ++e) acc[e] = 0.f;

  const float4* xr = reinterpret_cast<const float4*>(x + (size_t)n * DM);
  for (int d4 = 0; d4 < DM / 4; ++d4) {
    float4 v = xr[d4];
    const float* gp = &gws[d4 * 4 * NE];
    float xv;
#pragma unroll
    for (int dd = 0; dd < 4; ++dd) {
      xv = (dd == 0) ? v.x : (dd == 1) ? v.y : (dd == 2) ? v.z : v.w;
#pragma unroll
      for (int e = 0; e < NE; ++e) acc[e] = fmaf(xv, gp[dd * NE + e], acc[e]);
    }
  }

  float mx = acc[0];
#pragma unroll
  for (int e = 1; e < NE; ++e) mx = fmaxf(mx, acc[e]);
  float p[NE], s = 0.f;
#pragma unroll
  for (int e = 0; e < NE; ++e) { p[e] = expf(acc[e] - mx); s += p[e]; }
  float inv = 1.f / s;
#pragma unroll
  for (int e = 0; e < NE; ++e) {
    float v = p[e] * inv;
#pragma unroll
    for (int o = 32; o > 0; o >>= 1) v += __shfl_xor(v, o);
    if ((tid & 63) == 0) atomicAdd(&psum[e], v);
  }

  float v0 = -1e30f, v1 = -1e30f; int i0 = 0, i1 = 0;
#pragma unroll
  for (int e = 0; e < NE; ++e) {
    float l = acc[e];
    if (l > v0) { v1 = v0; i1 = i0; v0 = l; i0 = e; }
    else if (l > v1) { v1 = l; i1 = e; }
  }
  float e1 = expf(v1 - v0);
  float den = 1.f + e1;
  pairW[n * 2]     = 1.f / den;
  pairW[n * 2 + 1] = e1 / den;
  int p0 = atomicAdd(&cnt[i0], 1); pairs[i0 * NTOK + p0] = n * 2;
  int p1 = atomicAdd(&cnt[i1], 1); pairs[i1 * NTOK + p1] = n * 2 + 1;
}

__global__ void finalize_kernel(const int* __restrict__ cnt, int* __restrict__ off,
                                const float* __restrict__ psum, float* __restrict__ aux)
{
  if (threadIdx.x == 0 && blockIdx.x == 0) {
    int o = 0;
    for (int e = 0; e < NE; ++e) { off[e] = o; o += cnt[e]; }
    off[NE] = o;
    float a = 0.f;
    for (int e = 0; e < NE; ++e) { float me = psum[e] * (1.f / NTOK); a += me * me; }
    aux[0] = a * (float)NE;
  }
}

// ---------------- prepass: x f32 -> bf16 ----------------
__global__ __launch_bounds__(256) void convert_x_kernel(
    const float* __restrict__ x, short* __restrict__ xb)
{
  const int i = (blockIdx.x * 256 + threadIdx.x) * 8;
  float4 a = *reinterpret_cast<const float4*>(&x[i]);
  float4 b = *reinterpret_cast<const float4*>(&x[i + 4]);
  union { short s[8]; bf16x8 v; } p;
  p.s[0]=to_bf16(a.x); p.s[1]=to_bf16(a.y); p.s[2]=to_bf16(a.z); p.s[3]=to_bf16(a.w);
  p.s[4]=to_bf16(b.x); p.s[5]=to_bf16(b.y); p.s[6]=to_bf16(b.z); p.s[7]=to_bf16(b.w);
  *reinterpret_cast<bf16x8*>(&xb[i]) = p.v;
}

// ---------------- prepass: transpose + convert weights ----------------
// w1[e] (DM x DFF) f32 -> w1t[e] (DFF x DM) bf16 ; w2[e] (DFF x DM) -> w2t[e] (DM x DFF)
__global__ __launch_bounds__(256) void transpose_kernel(
    const float* __restrict__ w1, const float* __restrict__ w2,
    short* __restrict__ w1t, short* __restrict__ w2t)
{
  const int z = blockIdx.z;
  const float* src; short* dst; int R, C, rt, ct;
  if (z < 8) { src = w1 + (size_t)z * DM * DFF; dst = w1t + (size_t)z * DM * DFF;
               R = DM; C = DFF; ct = blockIdx.x; rt = blockIdx.y; }
  else       { src = w2 + (size_t)(z - 8) * DM * DFF; dst = w2t + (size_t)(z - 8) * DM * DFF;
               R = DFF; C = DM; ct = blockIdx.y; rt = blockIdx.x; }
  const int r0 = rt * 64, c0 = ct * 64;
  __shared__ float t[64][65];
  const int tid = threadIdx.x;
  {
    const int row = tid >> 4;           // 0..15
    const int col = (tid & 15) * 4;
#pragma unroll
    for (int it = 0; it < 4; ++it) {
      float4 v = *reinterpret_cast<const float4*>(&src[(size_t)(r0 + it * 16 + row) * C + c0 + col]);
      t[it * 16 + row][col]     = v.x;
      t[it * 16 + row][col + 1] = v.y;
      t[it * 16 + row][col + 2] = v.z;
      t[it * 16 + row][col + 3] = v.w;
    }
  }
  __syncthreads();
  {
    const int oc  = tid >> 3;           // 0..31  (tile col -> out row)
    const int orr = (tid & 7) * 8;      // out col base
#pragma unroll
    for (int it = 0; it < 2; ++it) {
      union { short s[8]; bf16x8 v; } p;
#pragma unroll
      for (int j = 0; j < 8; ++j) p.s[j] = to_bf16(t[orr + j][it * 32 + oc]);
      *reinterpret_cast<bf16x8*>(&dst[(size_t)(c0 + it * 32 + oc) * R + r0 + orr]) = p.v;
    }
  }
}

// ---------------- GEMM1: h = gelu(gather(xb) @ w1t[e]^T) ----------------
__global__ __launch_bounds__(256) void gemm1_kernel(
    const short* __restrict__ xb, const short* __restrict__ w1t,
    const int* __restrict__ cnt, const int* __restrict__ off,
    const int* __restrict__ pairs, short* __restrict__ h)
{
  // bijective XCD-chunked swizzle; order (ff, e, m) => chunk = 4 ff x 8 e x 32 m
  const int wg = (blockIdx.x & 7) * 1024 + (blockIdx.x >> 3);
  const int m0  = (wg & 31) * 128;
  const int e   = (wg >> 5) & 7;
  const int ff0 = (wg >> 8) * 128;
  const int M = cnt[e];
  if (m0 >= M) return;
  const int base = off[e];

  __shared__ __attribute__((aligned(16))) short As[128 * 32];
  __shared__ __attribute__((aligned(16))) short Bs[128 * 32];

  const int tid  = threadIdx.x;
  const int lane = tid & 63;
  const int w    = tid >> 6;
  const int wm = w >> 1, wn = w & 1;

  // staging: 2 issues/wave for A, 2 for B; each covers 16 rows x 32 k
  const int srow0 = (w * 2 + 0) * 16 + (lane >> 2);
  const int srow1 = (w * 2 + 1) * 16 + (lane >> 2);
  const int skoff = (lane & 3) * 8;
  int gi0 = m0 + srow0; if (gi0 > M - 1) gi0 = M - 1;
  int gi1 = m0 + srow1; if (gi1 > M - 1) gi1 = M - 1;
  const int tok0 = pairs[e * NTOK + gi0] >> 1;
  const int tok1 = pairs[e * NTOK + gi1] >> 1;
  const short* ga0 = xb + (size_t)tok0 * DM + skoff;
  const short* ga1 = xb + (size_t)tok1 * DM + skoff;
  const short* gb0 = w1t + ((size_t)e * DFF + ff0 + srow0) * DM + skoff;
  const short* gb1 = w1t + ((size_t)e * DFF + ff0 + srow1) * DM + skoff;
  short* la0 = As + (w * 2 + 0) * 512;
  short* la1 = As + (w * 2 + 1) * 512;
  short* lb0 = Bs + (w * 2 + 0) * 512;
  short* lb1 = Bs + (w * 2 + 1) * 512;

  f32x4 acc[4][4];
#pragma unroll
  for (int i = 0; i < 4; ++i)
#pragma unroll
    for (int j = 0; j < 4; ++j) acc[i][j] = (f32x4){0.f, 0.f, 0.f, 0.f};

  const int lrow = lane & 15;
  const int lk   = (lane >> 4) * 8;

  for (int k0 = 0; k0 < DM; k0 += 32) {
    gl16(ga0 + k0, la0);
    gl16(ga1 + k0, la1);
    gl16(gb0 + k0, lb0);
    gl16(gb1 + k0, lb1);
    __syncthreads();

    bf16x8 af[4], bfv[4];
#pragma unroll
    for (int i = 0; i < 4; ++i)
      af[i] = *reinterpret_cast<const bf16x8*>(&As[(wm * 64 + i * 16 + lrow) * 32 + lk]);
#pragma unroll
    for (int j = 0; j < 4; ++j)
      bfv[j] = *reinterpret_cast<const bf16x8*>(&Bs[(wn * 64 + j * 16 + lrow) * 32 + lk]);
#pragma unroll
    for (int i = 0; i < 4; ++i)
#pragma unroll
      for (int j = 0; j < 4; ++j)
        acc[i][j] = __builtin_amdgcn_mfma_f32_16x16x32_bf16(af[i], bfv[j], acc[i][j], 0, 0, 0);

    __syncthreads();
  }

  const int rbase = wm * 64 + (lane >> 4) * 4;
  const int cb    = ff0 + wn * 64 + (lane & 15);
#pragma unroll
  for (int i = 0; i < 4; ++i) {
#pragma unroll
    for (int r = 0; r < 4; ++r) {
      const int grow = m0 + rbase + i * 16 + r;
      if (grow < M) {
#pragma unroll
        for (int j = 0; j < 4; ++j) {
          float v = acc[i][j][r];
          float g = 0.5f * v * (1.f + erff(v * 0.70710678118f));
          h[(size_t)(base + grow) * DFF + cb + j * 16] = to_bf16(g);
        }
      }
    }
  }
}

// ---------------- GEMM2: out += weight * (h @ w2t[e]^T) ----------------
__global__ __launch_bounds__(256) void gemm2_kernel(
    const short* __restrict__ h, const short* __restrict__ w2t,
    const int* __restrict__ cnt, const int* __restrict__ off,
    const int* __restrict__ pairs, const float* __restrict__ pairW,
    float* __restrict__ out)
{
  // order (d, e, m) => chunk = 1 d x 8 e x 32 m
  const int wg = (blockIdx.x & 7) * 256 + (blockIdx.x >> 3);
  const int m0 = (wg & 31) * 128;
  const int e  = (wg >> 5) & 7;
  const int d0 = (wg >> 8) * 128;
  const int M = cnt[e];
  if (m0 >= M) return;
  const int base = off[e];

  __shared__ __attribute__((aligned(16))) short As[128 * 32];
  __shared__ __attribute__((aligned(16))) short Bs[128 * 32];

  const int tid  = threadIdx.x;
  const int lane = tid & 63;
  const int w    = tid >> 6;
  const int wm = w >> 1, wn = w & 1;

  const int srow0 = (w * 2 + 0) * 16 + (lane >> 2);
  const int srow1 = (w * 2 + 1) * 16 + (lane >> 2);
  const int skoff = (lane & 3) * 8;
  int gi0 = m0 + srow0; if (gi0 > M - 1) gi0 = M - 1;
  int gi1 = m0 + srow1; if (gi1 > M - 1) gi1 = M - 1;
  const short* ga0 = h + (size_t)(base + gi0) * DFF + skoff;
  const short* ga1 = h + (size_t)(base + gi1) * DFF + skoff;
  const short* gb0 = w2t + ((size_t)e * DM + d0 + srow0) * DFF + skoff;
  const short* gb1 = w2t + ((size_t)e * DM + d0 + srow1) * DFF + skoff;
  short* la0 = As + (w * 2 + 0) * 512;
  short* la1 = As + (w * 2 + 1) * 512;
  short* lb0 = Bs + (w * 2 + 0) * 512;
  short* lb1 = Bs + (w * 2 + 1) * 512;

  f32x4 acc[4][4];
#pragma unroll
  for (int i = 0; i < 4; ++i)
#pragma unroll
    for (int j = 0; j < 4; ++j) acc[i][j] = (f32x4){0.f, 0.f, 0.f, 0.f};

  const int lrow = lane & 15;
  const int lk   = (lane >> 4) * 8;

  for (int k0 = 0; k0 < DFF; k0 += 32) {
    gl16(ga0 + k0, la0);
    gl16(ga1 + k0, la1);
    gl16(gb0 + k0, lb0);
    gl16(gb1 + k0, lb1);
    __syncthreads();

    bf16x8 af[4], bfv[4];
#pragma unroll
    for (int i = 0; i < 4; ++i)
      af[i] = *reinterpret_cast<const bf16x8*>(&As[(wm * 64 + i * 16 + lrow) * 32 + lk]);
#pragma unroll
    for (int j = 0; j < 4; ++j)
      bfv[j] = *reinterpret_cast<const bf16x8*>(&Bs[(wn * 64 + j * 16 + lrow) * 32 + lk]);
#pragma unroll
    for (int i = 0; i < 4; ++i)
#pragma unroll
      for (int j = 0; j < 4; ++j)
        acc[i][j] = __builtin_amdgcn_mfma_f32_16x16x32_bf16(af[i], bfv[j], acc[i][j], 0, 0, 0);

    __syncthreads();
  }

  const int rbase = wm * 64 + (lane >> 4) * 4;
  const int cb    = d0 + wn * 64 + (lane & 15);
#pragma unroll
  for (int i = 0; i < 4; ++i) {
#pragma unroll
    for (int r = 0; r < 4; ++r) {
      const int grow = m0 + rbase + i * 16 + r;
      if (grow < M) {
        const int pr  = pairs[e * NTOK + grow];
        const float wgt = pairW[pr];
        const int tk  = pr >> 1;
#pragma unroll
        for (int j = 0; j < 4; ++j)
          atomicAdd(&out[(size_t)tk * DM + cb + j * 16], wgt * acc[i][j][r]);
      }
    }
  }
}

extern "C" void kernel_launch(void* const* d_in, const int* in_sizes, int n_in,
                              void* d_out, int out_size, void* d_ws, size_t ws_size,
                              hipStream_t stream)
{
  const float* x  = (const float*)d_in[0];
  const float* gw = (const float*)d_in[1];
  const float* w1 = (const float*)d_in[2];
  const float* w2 = (const float*)d_in[3];
  float* outf = (float*)d_out;

  int*   cnt   = (int*)d_ws;                                   // 8
  int*   off   = cnt + 8;                                      // 9
  float* psum  = (float*)(cnt + 20);                           // 8
  int*   pairs = (int*)((char*)d_ws + 512);                    // 8*4096 ints (128KB)
  float* pairW = (float*)((char*)d_ws + 512 + NE * NTOK * 4);  // 8192 floats
  short* xb    = (short*)((char*)d_ws + (size_t)(1)  * (1 << 20));   // 8 MB
  short* w1t   = (short*)((char*)d_ws + (size_t)(16) * (1 << 20));   // 64 MB
  short* w2t   = (short*)((char*)d_ws + (size_t)(80) * (1 << 20));   // 64 MB
  short* h     = (short*)((char*)d_ws + (size_t)(144)* (1 << 20));   // 64 MB

  hipMemsetAsync(d_ws, 0, 512, stream);
  hipMemsetAsync(d_out, 0, (size_t)out_size * sizeof(float), stream);

  router_kernel<<<NTOK / 256, 256, 0, stream>>>(x, gw, cnt, psum, pairs, pairW);
  finalize_kernel<<<1, 64, 0, stream>>>(cnt, off, psum, outf + (size_t)NTOK * DM);
  convert_x_kernel<<<NTOK * DM / (256 * 8), 256, 0, stream>>>(x, xb);
  transpose_kernel<<<dim3(64, 16, 16), 256, 0, stream>>>(w1, w2, w1t, w2t);
  gemm1_kernel<<<8192, 256, 0, stream>>>(xb, w1t, cnt, off, pairs, h);
  gemm2_kernel<<<2048, 256, 0, stream>>>(h, w2t, cnt, off, pairs, pairW, outf);
}